// Round 1
// baseline (402.527 us; speedup 1.0000x reference)
//
#include <hip/hip_runtime.h>

typedef int v4i __attribute__((ext_vector_type(4)));
typedef int v16i __attribute__((ext_vector_type(16)));

#define IN_F   3072
#define PAD    4096
#define M_ROWS 8192
#define N_OUT  4096

#define BM 128
#define BN 256
#define BK 64

// ---------------------------------------------------------------------------
// async 16B global -> LDS copy. Integer round-trip casts: guaranteed to
// compile; LDS aperture on gfx9 is 4GB-aligned so low-32 truncation of the
// flat address IS the LDS offset. HW dest = wave-uniform base + lane*16.
// ---------------------------------------------------------------------------
__device__ __forceinline__ void async_copy16(const void* g, void* l) {
    __builtin_amdgcn_global_load_lds(
        (__attribute__((address_space(1))) const void*)(uintptr_t)g,
        (__attribute__((address_space(3))) void*)(uint32_t)(uintptr_t)l,
        16, 0, 0);
}

// unnormalized FWHT over 16 register values
__device__ __forceinline__ void fwht16(float v[16]) {
#pragma unroll
    for (int s = 1; s < 16; s <<= 1) {
#pragma unroll
        for (int i = 0; i < 16; i++) {
            if ((i & s) == 0) {
                float a = v[i], b = v[i ^ s];
                v[i]     = a + b;
                v[i ^ s] = a - b;
            }
        }
    }
}

// ---------------------------------------------------------------------------
// One row per block: load 3072 floats (zero-pad to 4096), FWHT-4096 as
// FWHT16 (x) FWHT16 (x) FWHT16 with two XOR-swizzled LDS exchanges
// (<=2-way bank aliasing on every access = free), then 8-bit affine
// quantize; store (q-128) as int8 and the row sum of (q-128).
// index decomposition: k = 256*k2 + 16*k1 + k0
// ---------------------------------------------------------------------------
__global__ __launch_bounds__(256) void fwht_quant_kernel(
    const float* __restrict__ in, signed char* __restrict__ qout,
    int* __restrict__ rowsum, int nrows)
{
    __shared__ float lds[4096];
    __shared__ int ssum;
    const int t = threadIdx.x;
    const int r = blockIdx.x;
    if (r >= nrows) return;
    const float* row = in + (size_t)r * IN_F;

    // load: reg j (=k2) holds element 256*j + t  (perfectly coalesced; 3072 = 12*256)
    float v[16];
#pragma unroll
    for (int j = 0; j < 16; j++)
        v[j] = (j < 12) ? row[j * 256 + t] : 0.0f;

    fwht16(v);                      // over k2

    const int th = t >> 4, tl = t & 15;   // (k1,k0) for now

    // exchange 1: layout phys(k2,k1,k0) = 256*k2 + 16*(k1^k2) + (k0^k1)
    #pragma unroll
    for (int j = 0; j < 16; j++)
        lds[256 * j + 16 * (th ^ j) + (tl ^ th)] = v[j];   // (k2=j,k1=th,k0=tl)
    __syncthreads();
#pragma unroll
    for (int j = 0; j < 16; j++)                            // now (k2=th,k0=tl), regs k1
        v[j] = lds[256 * th + 16 * (j ^ th) + (tl ^ j)];

    fwht16(v);                      // over k1

    if (t == 0) ssum = 0;
    __syncthreads();                // protects lds reuse + ssum init

    // exchange 2: layout phys(k2,k1,k0) = 256*k2 + 16*(k1^k2) + (k0^k1)
#pragma unroll
    for (int j = 0; j < 16; j++)                            // (k2=th,k1=j,k0=tl)
        lds[256 * th + 16 * (j ^ th) + (tl ^ j)] = v[j];
    __syncthreads();
#pragma unroll
    for (int j = 0; j < 16; j++)                            // now (k2=th,k1=tl), regs k0
        v[j] = lds[256 * th + 16 * (tl ^ th) + (j ^ tl)];

    fwht16(v);                      // over k0 -> thread t holds elements [16t,16t+16)

    // quantize: q = clip(round((clip(x,+-384)+384)/s),0,255); store a=q-128
    // 1/s = 255/768 = 85/256 exactly representable in f32
    const float INV = 0.33203125f;
    int sum = 0;
    int pk[4];
#pragma unroll
    for (int c = 0; c < 4; c++) {
        int word = 0;
#pragma unroll
        for (int b = 0; b < 4; b++) {
            float x = v[c * 4 + b];
            x = fminf(fmaxf(x, -384.0f), 384.0f);
            float qf = rintf((x + 384.0f) * INV);
            int qi = (int)qf;
            qi = qi < 0 ? 0 : (qi > 255 ? 255 : qi);
            int a = qi - 128;
            sum += a;
            word |= (a & 255) << (8 * b);
        }
        pk[c] = word;
    }

    // row-sum: wave shuffle reduce, then one LDS atomic per wave
#pragma unroll
    for (int off = 32; off > 0; off >>= 1) sum += __shfl_down(sum, off, 64);
    if ((t & 63) == 0) atomicAdd(&ssum, sum);

    ((int4*)(qout + (size_t)r * PAD))[t] = make_int4(pk[0], pk[1], pk[2], pk[3]);

    __syncthreads();
    if (t == 0) rowsum[r] = ssum;
}

// ---------------------------------------------------------------------------
// int8 GEMM: C[m,n] = sum_k A[m,k]*B[n,k] (both K-major), then affine fixup.
// Block tile 128x256, BK=64 bytes, 4 waves each 64x128 (2x4 mfma 32x32x32).
// LDS rows hold 64B (4 chunks of 16B) with rotation swizzle: physical chunk
// p of row r stores logical chunk (p - r) & 3  -> frag ds_read_b128 is
// bank-conflict-free; global_load_lds staging is sequential-chunk by
// construction.
// epilogue: out = D*kA + (SA[m]+SB[n])*kS + kC + bias[n]
// ---------------------------------------------------------------------------
__global__ __launch_bounds__(256, 2) void gemm_i8_kernel(
    const signed char* __restrict__ A, const signed char* __restrict__ B,
    const int* __restrict__ SA, const int* __restrict__ SB,
    const float* __restrict__ bias, float* __restrict__ out,
    float kA, float kS, float kC)
{
    __shared__ __align__(16) signed char As[BM * BK];
    __shared__ __align__(16) signed char Bs[BN * BK];

    const int tid  = threadIdx.x;
    const int lane = tid & 63;
    const int wid  = tid >> 6;
    const int wr   = wid >> 1, wc = wid & 1;
    const int bm   = blockIdx.y * BM;
    const int bn   = blockIdx.x * BN;
    const int l5   = lane >> 5;     // 0/1 half-wave
    const int lm   = lane & 31;     // mfma row/col lane

    v16i acc[2][4];
#pragma unroll
    for (int i = 0; i < 2; i++)
#pragma unroll
        for (int j = 0; j < 4; j++)
#pragma unroll
            for (int e = 0; e < 16; e++)
                acc[i][j][e] = 0;

    for (int bk = 0; bk < PAD; bk += BK) {
        // ---- stage A: 128 rows x 64B = 512 chunks, 2 insts/wave ----
#pragma unroll
        for (int i = 0; i < 2; i++) {
            int c = wid * 128 + i * 64 + lane;
            int rr = c >> 2, p = c & 3;
            int q = (p - rr) & 3;                 // logical chunk stored at p
            async_copy16(A + (size_t)(bm + rr) * PAD + bk + q * 16,
                         As + (wid * 128 + i * 64) * 16);
        }
        // ---- stage B: 256 rows x 64B = 1024 chunks, 4 insts/wave ----
#pragma unroll
        for (int i = 0; i < 4; i++) {
            int c = wid * 256 + i * 64 + lane;
            int rr = c >> 2, p = c & 3;
            int q = (p - rr) & 3;
            async_copy16(B + (size_t)(bn + rr) * PAD + bk + q * 16,
                         Bs + (wid * 256 + i * 64) * 16);
        }
        __syncthreads();

        // ---- compute: 2 k-steps of 32, 8 mfma each ----
#pragma unroll
        for (int ks = 0; ks < 2; ks++) {
            const int qbase = ks * 2 + l5;        // logical 16B chunk for this lane-half
            v4i a[2], b[4];
#pragma unroll
            for (int mt = 0; mt < 2; mt++) {
                int rr = wr * 64 + mt * 32 + lm;
                int p = (qbase + rr) & 3;
                a[mt] = *(const v4i*)(As + rr * 64 + p * 16);
            }
#pragma unroll
            for (int nt = 0; nt < 4; nt++) {
                int rr = wc * 128 + nt * 32 + lm;
                int p = (qbase + rr) & 3;
                b[nt] = *(const v4i*)(Bs + rr * 64 + p * 16);
            }
#pragma unroll
            for (int mt = 0; mt < 2; mt++)
#pragma unroll
                for (int nt = 0; nt < 4; nt++)
                    acc[mt][nt] = __builtin_amdgcn_mfma_i32_32x32x32_i8(
                        a[mt], b[nt], acc[mt][nt], 0, 0, 0);
        }
        __syncthreads();
    }

    // ---- epilogue: C/D layout col=lane&31, row=(e&3)+8*(e>>2)+4*(lane>>5) ----
#pragma unroll
    for (int nt = 0; nt < 4; nt++) {
        int n = bn + wc * 128 + nt * 32 + lm;
        float ct = (float)SB[n] * kS + kC + bias[n];
#pragma unroll
        for (int mt = 0; mt < 2; mt++) {
#pragma unroll
            for (int e = 0; e < 16; e++) {
                int m = bm + wr * 64 + mt * 32 + l5 * 4 + (e & 3) + 8 * (e >> 2);
                out[(size_t)m * N_OUT + n] =
                    (float)acc[mt][nt][e] * kA + (float)SA[m] * kS + ct;
            }
        }
    }
}

// ---------------------------------------------------------------------------
extern "C" void kernel_launch(void* const* d_in, const int* in_sizes, int n_in,
                              void* d_out, int out_size, void* d_ws, size_t ws_size,
                              hipStream_t stream) {
    const float* x    = (const float*)d_in[0];   // [2,4096,3072]
    const float* w    = (const float*)d_in[1];   // [4096,3072]
    const float* bias = (const float*)d_in[2];   // [4096]
    float* out = (float*)d_out;                  // [2,4096,4096]

    // workspace: qa 32MB | qb 16MB | SA 32KB | SB 16KB  (~48MB total)
    signed char* qa = (signed char*)d_ws;
    signed char* qb = qa + (size_t)M_ROWS * PAD;
    int* SA = (int*)(qb + (size_t)N_OUT * PAD);
    int* SB = SA + M_ROWS;

    fwht_quant_kernel<<<M_ROWS, 256, 0, stream>>>(x, qa, SA, M_ROWS);
    fwht_quant_kernel<<<N_OUT,  256, 0, stream>>>(w, qb, SB, N_OUT);

    // out = (s^2*D + s*c*(SA+SB) + K*c^2)/K + bias,  s=768/255, c=128s-384=384/255
    double s = 768.0 / 255.0;
    double c = 384.0 / 255.0;
    float kA = (float)(s * s / PAD);
    float kS = (float)(s * c / PAD);
    float kC = (float)(c * c);

    dim3 grid(N_OUT / BN, M_ROWS / BM);
    gemm_i8_kernel<<<grid, 256, 0, stream>>>(qa, qb, SA, SB, bias, out, kA, kS, kC);
}